// Round 5
// baseline (393.699 us; speedup 1.0000x reference)
//
#include <hip/hip_runtime.h>
#include <cstdint>

#define K_SEL 4768
#define CAND_CAP 16384
#define NBIN 4096
#define TPAD 9216   // padded-triangular T words per (img,lvl): 64 * sum((c+1)|1, c=0..15)

struct P5 { const float* p[5]; };

__device__ __forceinline__ unsigned fsortkey(float f) {
  unsigned b = __float_as_uint(f);
  return (b & 0x80000000u) ? ~b : (b | 0x80000000u);
}

// ------- histogram of sortable-logit top-12 bits per (img,lvl): per-block partials ------
// kept as a SEPARATE massively-parallel kernel: fusing into 1 block/p would serialize
// ~196k contended LDS atomics (normal data concentrates in ~dozens of hot bins).
__global__ __launch_bounds__(256) void k_hist(P5 obj, unsigned* phist) {
  int p = blockIdx.y; int img = p / 5, lvl = p % 5;
  int f = 256 >> lvl; int n = 3 * f * f;
  __shared__ unsigned lh[NBIN];
  for (int b = threadIdx.x; b < NBIN; b += 256) lh[b] = 0;
  __syncthreads();
  const float4* src4 = (const float4*)(obj.p[lvl] + (size_t)img * n);
  int n4 = n >> 2;
  int chunk = (n4 + gridDim.x - 1) / gridDim.x;
  int e0 = blockIdx.x * chunk, e1 = min(n4, e0 + chunk);
  for (int e = e0 + threadIdx.x; e < e1; e += 256) {
    float4 v = src4[e];
    atomicAdd(&lh[fsortkey(v.x) >> 20], 1u);
    atomicAdd(&lh[fsortkey(v.y) >> 20], 1u);
    atomicAdd(&lh[fsortkey(v.z) >> 20], 1u);
    atomicAdd(&lh[fsortkey(v.w) >> 20], 1u);
  }
  __syncthreads();
  unsigned* dst = phist + ((size_t)(p * 8 + blockIdx.x)) * NBIN;
  for (int b = threadIdx.x; b < NBIN; b += 256) dst[b] = lh[b];   // unconditional: no pre-zero
}

// ------- FUSED: threshold + gather + exact top-kk select, one block per (img,lvl) -------
// thresh: sum 8 partials -> hsum/csum -> thread0 scan -> B (LDS broadcast).
// gather: re-read obj (L2-warm from k_hist), candidates into sk[] via one leader-atomic
//         per wave-ballot (order-independent; keys unique). Spill >4096 to global (rare).
// select: rank-count each candidate vs all staged (+tail), write selSV/selIdx.
__global__ __launch_bounds__(256) void k_tgsel(P5 obj, const unsigned* phist,
                                               unsigned long long* ck,
                                               unsigned* selSV, unsigned* selIdx) {
  int p = blockIdx.x; int img = p / 5, lvl = p % 5;
  int f = 256 >> lvl; int hw = f * f; int n = 3 * hw;
  int kk = (lvl == 4) ? 768 : 1000;
  int tid = threadIdx.x;
  int lane = tid & 63;
  __shared__ unsigned hsum[NBIN];
  __shared__ unsigned csum[256];
  __shared__ unsigned long long sk[4096];
  __shared__ int Bs;
  __shared__ unsigned candCnt, ovf;
  // ---- thresh ----
  unsigned tot[16];
#pragma unroll
  for (int k = 0; k < 16; ++k) tot[k] = 0;
  for (int g = 0; g < 8; ++g) {
    const unsigned* hp = phist + ((size_t)(p * 8 + g)) * NBIN + tid * 16;
#pragma unroll
    for (int k = 0; k < 16; ++k) tot[k] += hp[k];
  }
  unsigned s = 0;
#pragma unroll
  for (int k = 0; k < 16; ++k) { hsum[tid * 16 + k] = tot[k]; s += tot[k]; }
  csum[tid] = s;
  if (tid == 0) { candCnt = 0; ovf = 0; }
  __syncthreads();
  if (tid == 0) {
    unsigned acc = 0; int B = 0;
    for (int cc = 255; cc >= 0; --cc) {
      if (acc + csum[cc] >= (unsigned)kk) {
        for (int b = 15; b >= 0; --b) {
          acc += hsum[cc * 16 + b];
          if (acc >= (unsigned)kk) { B = cc * 16 + b; break; }
        }
        break;
      }
      acc += csum[cc];
    }
    Bs = B;
  }
  __syncthreads();
  int B = Bs;
  // ---- gather ----
  int shift = 2 * (8 - lvl);
  const float4* src4 = (const float4*)(obj.p[lvl] + (size_t)img * n);
  int n4 = n >> 2;
  unsigned long long* dstG = ck + (size_t)p * CAND_CAP;   // spill region (rare)
  for (int e = tid; e < n4; e += 256) {
    float4 v = src4[e];
    float vv[4] = {v.x, v.y, v.z, v.w};
#pragma unroll
    for (int j = 0; j < 4; ++j) {
      unsigned sv = fsortkey(vv[j]);
      bool pass = (int)(sv >> 20) >= B;
      unsigned long long m = __ballot(pass);
      if (m) {
        int leader = __ffsll(m) - 1;
        unsigned base = 0;
        if (lane == leader) base = atomicAdd(&candCnt, (unsigned)__popcll(m));
        base = __shfl(base, leader);
        if (pass) {
          unsigned pos = base + (unsigned)__popcll(m & ((1ULL << lane) - 1ULL));
          int ee = e * 4 + j;
          int a = ee >> shift;                 // ee / hw
          int r = ee & (hw - 1);               // ee % hw
          unsigned kidx = (unsigned)(r * 3 + a); // reference flatten order (y*W+x)*A + a
          unsigned long long key = ((unsigned long long)sv << 32) | (0xFFFFFFFFu - kidx);
          if (pos < 4096u) sk[pos] = key;
          else {                               // pathological skew only
            unsigned gp = atomicAdd(&ovf, 1u);
            if (gp < CAND_CAP) dstG[gp] = key;
          }
        }
      }
    }
  }
  __threadfence_block();                       // make spill writes visible block-wide
  __syncthreads();
  // ---- select ----
  int Cc = min((int)candCnt, 4096);
  int Ct = min((int)ovf, CAND_CAP);
  int soff = lvl * 1000;
  for (int c = tid; c < Cc; c += 256) {
    unsigned long long kc = sk[c];
    int rank = 0;
#pragma unroll 8
    for (int j = 0; j < Cc; ++j) rank += (sk[j] > kc) ? 1 : 0;
    for (int j = 0; j < Ct; ++j) rank += (dstG[j] > kc) ? 1 : 0;
    if (rank < kk) {
      int slot = img * K_SEL + soff + rank;
      selSV[slot]  = (unsigned)(kc >> 32);
      selIdx[slot] = 0xFFFFFFFFu - (unsigned)kc;
    }
  }
  for (int c = tid; c < Ct; c += 256) {        // rank spill tail too (rare)
    unsigned long long kc = dstG[c];
    int rank = 0;
    for (int j = 0; j < Cc; ++j) rank += (sk[j] > kc) ? 1 : 0;
    for (int j = 0; j < Ct; ++j) rank += (dstG[j] > kc) ? 1 : 0;
    if (rank < kk) {
      int slot = img * K_SEL + soff + rank;
      selSV[slot]  = (unsigned)(kc >> 32);
      selIdx[slot] = 0xFFFFFFFFu - (unsigned)kc;
    }
  }
}

// ---------------- decode + clip + validity for the 4768 selected per image --------------
__global__ __launch_bounds__(256) void k_decode(P5 del, const float* anchors,
                                                const unsigned* selSV, const unsigned* selIdx,
                                                float* boxP, unsigned long long* keyP) {
  int i = blockIdx.x * 256 + threadIdx.x;
  if (i >= K_SEL) return;
  int img = blockIdx.y;
  int lvl = (i < 4000) ? (i / 1000) : 4;
  int f = 256 >> lvl, hw = f * f;
  const int aoffA[5] = {0, 196608, 245760, 258048, 261120};
  int slot = img * K_SEL + i;
  unsigned k = selIdx[slot];
  unsigned sv = selSV[slot];
  int a = (int)(k % 3u); int r = (int)(k / 3u);
  int y = r >> (8 - lvl); int x = r & (f - 1);
  const float* dp = del.p[lvl] + (size_t)(img * 12 + a * 4) * hw + (size_t)y * f + x;
  float d0 = dp[0], d1 = dp[hw], d2 = dp[2 * hw], d3 = dp[3 * hw];
  const float* ar = anchors + (size_t)(aoffA[lvl] + (int)k) * 4;
  float a0 = ar[0], a1 = ar[1], a2 = ar[2], a3 = ar[3];
  // numpy-faithful, no FMA contraction
  float w = __fsub_rn(a2, a0), h = __fsub_rn(a3, a1);
  float cx = __fadd_rn(a0, __fmul_rn(0.5f, w));
  float cy = __fadd_rn(a1, __fmul_rn(0.5f, h));
  const float CLIP = 4.135166556742356f;     // log(1000/16)
  float dw = fminf(d2, CLIP), dh = fminf(d3, CLIP);
  float pcx = __fadd_rn(__fmul_rn(d0, w), cx);
  float pcy = __fadd_rn(__fmul_rn(d1, h), cy);
  float pw = __fmul_rn(expf(dw), w);
  float ph = __fmul_rn(expf(dh), h);
  float x1 = __fsub_rn(pcx, __fmul_rn(0.5f, pw));
  float y1 = __fsub_rn(pcy, __fmul_rn(0.5f, ph));
  float x2 = __fadd_rn(pcx, __fmul_rn(0.5f, pw));
  float y2 = __fadd_rn(pcy, __fmul_rn(0.5f, ph));
  float x1c = fminf(fmaxf(x1, 0.0f), 1024.0f);
  float y1c = fminf(fmaxf(y1, 0.0f), 1024.0f);
  float x2c = fminf(fmaxf(x2, 0.0f), 1024.0f);
  float y2c = fminf(fmaxf(y2, 0.0f), 1024.0f);
  bool valid = (__fsub_rn(x2c, x1c) >= 1e-3f) && (__fsub_rn(y2c, y1c) >= 1e-3f);
  float* bp = boxP + (size_t)slot * 4;
  bp[0] = x1c; bp[1] = y1c; bp[2] = x2c; bp[3] = y2c;
  unsigned low = 0xFFFFFFFFu - (unsigned)i;   // pos asc tie-break, unique keys
  keyP[slot] = valid ? (((unsigned long long)sv << 32) | low) : (unsigned long long)low;
}

// ---------------- IoU on offset boxes, bitwise matching reference -----------------------
__device__ __forceinline__ bool iou_gt(float rx1, float ry1, float rx2, float ry2, float rar,
                                       float cx1, float cy1, float cx2, float cy2, float car) {
  float ltx = fmaxf(rx1, cx1), lty = fmaxf(ry1, cy1);
  float rbx = fminf(rx2, cx2), rby = fminf(ry2, cy2);
  float wx = fmaxf(__fsub_rn(rbx, ltx), 0.0f);
  float wy = fmaxf(__fsub_rn(rby, lty), 0.0f);
  float inter = __fmul_rn(wx, wy);
  float denom = __fadd_rn(__fsub_rn(__fadd_rn(rar, car), inter), 1e-9f);
  return __fdiv_rn(inter, denom) > 0.7f;
}

// ---- TRANSPOSED suppression mask T[i] = "which j<i suppress i", triangular-packed ------
__global__ __launch_bounds__(64) void k_lvlmask(const float* boxP, unsigned long long* T) {
  int img = blockIdx.y;
  int q = blockIdx.x;                        // 0..621 per image
  int lvl, q2;
  if (q < 544) { lvl = q / 136; q2 = q - lvl * 136; }
  else         { lvl = 4;       q2 = q - 544; }
  int kk = (lvl == 4) ? 768 : 1000;
  int nch = (kk + 63) >> 6;
  int rb = 0;
  while (q2 >= nch - rb) { q2 -= nch - rb; ++rb; }    // upper-tri (rb, cb>=rb)
  int cb = rb + q2;
  int t = threadIdx.x;
  float off = __fmul_rn((float)lvl, 1025.0f);
  const float4* b4 = (const float4*)boxP + (size_t)img * K_SEL + lvl * 1000;
  __shared__ float rx1s[64], ry1s[64], rx2s[64], ry2s[64], rars[64];
  int j = rb * 64 + t;                       // ROW box staged in LDS
  if (j < kk) {
    float4 bb = b4[j];
    float ox1 = __fadd_rn(bb.x, off), oy1 = __fadd_rn(bb.y, off);
    float ox2 = __fadd_rn(bb.z, off), oy2 = __fadd_rn(bb.w, off);
    rx1s[t] = ox1; ry1s[t] = oy1; rx2s[t] = ox2; ry2s[t] = oy2;
    rars[t] = __fmul_rn(__fsub_rn(ox2, ox1), __fsub_rn(oy2, oy1));
  }
  __syncthreads();
  int i = cb * 64 + t;                       // COLUMN box in registers
  if (i >= kk) return;
  float4 bb = b4[i];
  float cx1 = __fadd_rn(bb.x, off), cy1 = __fadd_rn(bb.y, off);
  float cx2 = __fadd_rn(bb.z, off), cy2 = __fadd_rn(bb.w, off);
  float car = __fmul_rn(__fsub_rn(cx2, cx1), __fsub_rn(cy2, cy1));
  int jmaxR = min(64, kk - rb * 64);
  int jend = (rb == cb) ? min(t, jmaxR) : jmaxR;      // diag: only rows jj < t
  unsigned long long bits = 0;
  for (int jj = 0; jj < jend; ++jj) {
    if (iou_gt(rx1s[jj], ry1s[jj], rx2s[jj], ry2s[jj], rars[jj], cx1, cy1, cx2, cy2, car))
      bits |= (1ULL << jj);
  }
  const int Pt[16] = {0, 1, 4, 7, 12, 17, 24, 31, 40, 49, 60, 71, 84, 97, 112, 127};
  int sc = (cb + 1) | 1;
  T[(size_t)(img * 5 + lvl) * TPAD + 64 * Pt[cb] + t * sc + rb] = bits;
}

// ---- FUSED: per-level NMS sweep (5 waves, one level each) + per-image merge ------------
// Sweep: r4's proven serial-chunk exact-prefix sweep, but direct-from-global with
// double-buffered register prefetch (no LDS staging, no idle waves). Keep-words go to
// LDS; one barrier; then the whole 320-thread block runs the merge/rank phase.
#define CURW(w) ((c & 1) ? tvB[w] : tvA[w])
#define NXTW(w) ((c & 1) ? tvA[w] : tvB[w])
__global__ __launch_bounds__(320, 1) void k_nmsmerge(const unsigned long long* keyP,
                                                     const unsigned long long* Tg_,
                                                     const float* boxP, float* out) {
  int img = blockIdx.x;
  int tid = threadIdx.x;
  int lane = tid & 63, wv = tid >> 6;        // wv 0..4 = level
  __shared__ unsigned long long kwS[80];
  __shared__ unsigned long long lkey[5000];  // level l at l*1000: compacted kept keys (desc)
  __shared__ int lpos[5000];                 // original within-image slot
  __shared__ int wp[5][17];
  const int Pt[16] = {0, 1, 4, 7, 12, 17, 24, 31, 40, 49, 60, 71, 84, 97, 112, 127};
  {
    int lvl = wv;
    int kk = (lvl == 4) ? 768 : 1000;
    int nch = (kk + 63) >> 6;
    const unsigned long long* Tp = Tg_ + (size_t)(img * 5 + lvl) * TPAD;
    const unsigned long long* kp = keyP + (size_t)img * K_SEL + lvl * 1000;
    // validity bits for all chunks (independent scattered loads, one wait)
    unsigned vmask = 0;
#pragma unroll
    for (int c = 0; c < 16; ++c) {
      int i = c * 64 + lane;
      bool v = (i < kk) && ((kp[min(i, kk - 1)] >> 32) != 0ULL);
      vmask |= v ? (1u << c) : 0u;
    }
    unsigned long long tvA[16], tvB[16];
    unsigned long long kw0=0,kw1=0,kw2=0,kw3=0,kw4=0,kw5=0,kw6=0,kw7=0,
                       kw8=0,kw9=0,kw10=0,kw11=0,kw12=0,kw13=0,kw14=0,kw15=0;
    tvA[0] = Tp[lane];                       // preload chunk 0 (Pt[0]=0, sc=1)
#pragma unroll
    for (int c = 0; c < 16; ++c) {
      if (c < nch) {
        if (c + 1 < nch) {                   // issue next chunk's loads (prefetch)
          int nb = 64 * Pt[c + 1] + lane * ((c + 2) | 1);
#pragma unroll
          for (int w = 0; w <= c + 1; ++w) NXTW(w) = Tp[nb + w];
        }
        unsigned long long a = 0;
        // kwN are compile-time-selected per unrolled c: only w<c terms
#pragma unroll
        for (int w = 0; w < c; ++w) {
          unsigned long long kv =
            (w==0)?kw0:(w==1)?kw1:(w==2)?kw2:(w==3)?kw3:(w==4)?kw4:(w==5)?kw5:
            (w==6)?kw6:(w==7)?kw7:(w==8)?kw8:(w==9)?kw9:(w==10)?kw10:(w==11)?kw11:
            (w==12)?kw12:(w==13)?kw13:(w==14)?kw14:kw15;
          a |= CURW(w) & kv;
        }
        unsigned long long colT = CURW(c);
        bool alive = ((vmask >> c) & 1u) && (a == 0ULL);
        unsigned long long keepm = 0ULL;
        unsigned long long actm = __ballot(alive);
        while (actm) {
          bool cank = alive && ((colT & actm) == 0ULL);  // no alive suppressor below t
          unsigned long long newk = __ballot(cank);
          keepm |= newk;
          alive = alive && !cank && ((colT & newk) == 0ULL);
          actm = __ballot(alive);
        }
        switch (c) {                          // static store of wave-uniform keep word
          case 0: kw0=keepm; break;  case 1: kw1=keepm; break;
          case 2: kw2=keepm; break;  case 3: kw3=keepm; break;
          case 4: kw4=keepm; break;  case 5: kw5=keepm; break;
          case 6: kw6=keepm; break;  case 7: kw7=keepm; break;
          case 8: kw8=keepm; break;  case 9: kw9=keepm; break;
          case 10: kw10=keepm; break; case 11: kw11=keepm; break;
          case 12: kw12=keepm; break; case 13: kw13=keepm; break;
          case 14: kw14=keepm; break; default: kw15=keepm; break;
        }
      }
    }
    if (lane == 0) {
      kwS[lvl*16+0]=kw0;  kwS[lvl*16+1]=kw1;  kwS[lvl*16+2]=kw2;  kwS[lvl*16+3]=kw3;
      kwS[lvl*16+4]=kw4;  kwS[lvl*16+5]=kw5;  kwS[lvl*16+6]=kw6;  kwS[lvl*16+7]=kw7;
      kwS[lvl*16+8]=kw8;  kwS[lvl*16+9]=kw9;  kwS[lvl*16+10]=kw10; kwS[lvl*16+11]=kw11;
      kwS[lvl*16+12]=kw12; kwS[lvl*16+13]=kw13; kwS[lvl*16+14]=kw14; kwS[lvl*16+15]=kw15;
    }
  }
  __syncthreads();
  // ---- merge phase (whole block) ----
  if (tid < 5) {
    int acc = 0;
    for (int w = 0; w < 16; ++w) { wp[tid][w] = acc; acc += (int)__popcll(kwS[tid * 16 + w]); }
    wp[tid][16] = acc;
  }
  __syncthreads();
  const unsigned long long* kp = keyP + (size_t)img * K_SEL;
  for (int i = tid; i < K_SEL; i += 320) {
    int l = (i < 4000) ? i / 1000 : 4;
    int li = i - l * 1000;
    unsigned long long wmask = kwS[l * 16 + (li >> 6)];
    if ((wmask >> (li & 63)) & 1ULL) {
      int j = wp[l][li >> 6] + (int)__popcll(wmask & ((1ULL << (li & 63)) - 1ULL));
      lkey[l * 1000 + j] = kp[i];
      lpos[l * 1000 + j] = i;
    }
  }
  __syncthreads();
  const float4* b4 = (const float4*)boxP + (size_t)img * K_SEL;
  float4* out4 = (float4*)out + (size_t)img * 1000;
  for (int x = tid; x < 5000; x += 320) {
    int l = x / 1000, j = x - l * 1000;
    if (j >= wp[l][16]) continue;
    unsigned long long key = lkey[x];
    int grank = j;
#pragma unroll
    for (int l2 = 0; l2 < 5; ++l2) {
      if (l2 == l) continue;
      int lo = 0, hi = wp[l2][16];
      const unsigned long long* a = &lkey[l2 * 1000];
      while (lo < hi) { int mid = (lo + hi) >> 1; if (a[mid] > key) lo = mid + 1; else hi = mid; }
      grank += lo;                            // count of keys > key in level l2
    }
    if (grank < 1000) out4[grank] = b4[lpos[x]];
  }
  int KT = wp[0][16] + wp[1][16] + wp[2][16] + wp[3][16] + wp[4][16];
  for (int s = min(KT, 1000) + tid; s < 1000; s += 320)
    out4[s] = make_float4(0.f, 0.f, 0.f, 0.f);            // zero-pad tail
}

extern "C" void kernel_launch(void* const* d_in, const int* in_sizes, int n_in,
                              void* d_out, int out_size, void* d_ws, size_t ws_size,
                              hipStream_t stream) {
  (void)in_sizes; (void)n_in;
  // setup_inputs() dict order is INTERLEAVED: obj_l0, delta_l0, obj_l1, delta_l1, ..., anchors
  P5 obj, del;
  for (int i = 0; i < 5; ++i) {
    obj.p[i] = (const float*)d_in[2 * i];
    del.p[i] = (const float*)d_in[2 * i + 1];
  }
  const float* anchors = (const float*)d_in[10];
  float* out = (float*)d_out;
  char* ws = (char*)d_ws;

  // ws layout (bytes)
  unsigned long long* candK   = (unsigned long long*)(ws + 512);       // spill only now
  unsigned* selSV             = (unsigned*)(ws + 5243392);             // 152576 -> 5395968
  unsigned* selIdx            = (unsigned*)(ws + 5395968);             // 152576 -> 5548544
  float* boxP                 = (float*)(ws + 5548544);                // 610304 -> 6158848
  unsigned long long* keyP    = (unsigned long long*)(ws + 6158848);   // 305152 -> 6464000
  unsigned long long* T       = (unsigned long long*)(ws + 6469120);   // 40*9216*8 = 2949120 -> 9418240
  unsigned* phist             = (unsigned*)(ws + 6469120);             // overlay on T (dead before k_lvlmask): 5242880 -> 11712000
  const size_t NEED = 11712000ULL;
  if (ws_size < NEED) { hipMemsetAsync(d_out, 0, (size_t)out_size * 4, stream); return; }

  k_hist     <<<dim3(8, 40), 256, 0, stream>>>(obj, phist);
  k_tgsel    <<<40, 256, 0, stream>>>(obj, phist, candK, selSV, selIdx);
  k_decode   <<<dim3(19, 8), 256, 0, stream>>>(del, anchors, selSV, selIdx, boxP, keyP);
  k_lvlmask  <<<dim3(622, 8), 64, 0, stream>>>(boxP, T);
  k_nmsmerge <<<8, 320, 0, stream>>>(keyP, T, boxP, out);
}